// Round 1
// baseline (446.664 us; speedup 1.0000x reference)
//
#include <hip/hip_runtime.h>
#include <hip/hip_bf16.h>

#define NB 4
#define NN 256
#define ND 256
#define NK 1024
#define LOG2E 1.4426950408889634f

typedef __bf16 bf16x8 __attribute__((ext_vector_type(8)));
typedef float f32x4 __attribute__((ext_vector_type(4)));

__device__ __forceinline__ float blo(unsigned u) { return __uint_as_float(u << 16); }
__device__ __forceinline__ float bhi(unsigned u) { return __uint_as_float(u & 0xffff0000u); }

__global__ void zero_acc_kernel(float* acc) {
  if (threadIdx.x < 2) acc[threadIdx.x] = 0.0f;
}

// h = g @ patterns (bf16 MFMA), fused epilogue: E = bf16(exp(beta*h))
// One wave computes a 16x16 tile of h; block = 4 waves = 16(m) x 64(n).
__global__ __launch_bounds__(256) void gemm_exp_kernel(
    const float* __restrict__ A,   // g flattened (B*N, D) = (1024, 256)
    const float* __restrict__ P,   // patterns (D, K) = (256, 1024)
    const float* __restrict__ beta,
    ushort* __restrict__ E) {      // (1024, 1024) bf16 bits
  const int lane = threadIdx.x & 63;
  const int w = threadIdx.x >> 6;
  const int m0 = blockIdx.x * 16;
  const int n0 = blockIdx.y * 64 + w * 16;
  const int r15 = lane & 15;
  const int g4 = lane >> 4;
  const int arow = m0 + r15;
  const int bcol = n0 + r15;

  f32x4 acc = {0.f, 0.f, 0.f, 0.f};
#pragma unroll
  for (int kk = 0; kk < ND; kk += 32) {
    const int kb = kk + g4 * 8;  // same (group,elem)->k map for A and B => layout-safe
    const float* ap = A + arow * ND + kb;
    const float4 a0 = *(const float4*)ap;
    const float4 a1 = *(const float4*)(ap + 4);
    const float* pp = P + kb * NK + bcol;
    bf16x8 af, bfr;
    af[0] = (__bf16)a0.x; af[1] = (__bf16)a0.y; af[2] = (__bf16)a0.z; af[3] = (__bf16)a0.w;
    af[4] = (__bf16)a1.x; af[5] = (__bf16)a1.y; af[6] = (__bf16)a1.z; af[7] = (__bf16)a1.w;
    bfr[0] = (__bf16)pp[0 * NK]; bfr[1] = (__bf16)pp[1 * NK];
    bfr[2] = (__bf16)pp[2 * NK]; bfr[3] = (__bf16)pp[3 * NK];
    bfr[4] = (__bf16)pp[4 * NK]; bfr[5] = (__bf16)pp[5 * NK];
    bfr[6] = (__bf16)pp[6 * NK]; bfr[7] = (__bf16)pp[7 * NK];
    acc = __builtin_amdgcn_mfma_f32_16x16x32_bf16(af, bfr, acc, 0, 0, 0);
  }
  const float c = beta[0] * LOG2E;
#pragma unroll
  for (int r = 0; r < 4; ++r) {
    const int orow = m0 + g4 * 4 + r;   // C/D: col = lane&15, row = (lane>>4)*4 + r (HW-verified)
    const float e = exp2f(c * acc[r]);
    const __bf16 v = (__bf16)e;
    E[orow * NK + bcol] = __builtin_bit_cast(unsigned short, v);
  }
}

// One wave per (batch, edge): lse = ln( dot(E[b,v0,:], E[b,v1,:]) )
__global__ __launch_bounds__(256) void edge_lse_kernel(
    const ushort* __restrict__ E, const int* __restrict__ edges,
    const int m_edge, float* __restrict__ acc) {
  __shared__ float part[4];
  const int lane = threadIdx.x & 63;
  const int w = threadIdx.x >> 6;
  const int task = blockIdx.x * 4 + w;
  float lse = 0.0f;
  if (task < NB * m_edge) {
    const int b = task / m_edge;
    const int e = task - b * m_edge;
    const int v0 = edges[2 * e];
    const int v1 = edges[2 * e + 1];
    const uint4* r0 = (const uint4*)(E + (((size_t)(b * NN + v0)) << 10));
    const uint4* r1 = (const uint4*)(E + (((size_t)(b * NN + v1)) << 10));
    float s = 0.0f;
#pragma unroll
    for (int j = 0; j < 2; ++j) {
      const int idx = lane + j * 64;       // 128 uint4 per row, coalesced
      const uint4 ua = r0[idx];
      const uint4 ub = r1[idx];
      s = fmaf(blo(ua.x), blo(ub.x), s);
      s = fmaf(bhi(ua.x), bhi(ub.x), s);
      s = fmaf(blo(ua.y), blo(ub.y), s);
      s = fmaf(bhi(ua.y), bhi(ub.y), s);
      s = fmaf(blo(ua.z), blo(ub.z), s);
      s = fmaf(bhi(ua.z), bhi(ub.z), s);
      s = fmaf(blo(ua.w), blo(ub.w), s);
      s = fmaf(bhi(ua.w), bhi(ub.w), s);
    }
#pragma unroll
    for (int m = 32; m >= 1; m >>= 1) s += __shfl_xor(s, m, 64);
    lse = logf(s);
  }
  if (lane == 0) part[w] = lse;
  __syncthreads();
  if (threadIdx.x == 0) atomicAdd(acc, part[0] + part[1] + part[2] + part[3]);
}

// One wave per (batch, triangle): lse = ln( sum_k E0*E1*E2 )
__global__ __launch_bounds__(256) void tri_lse_kernel(
    const ushort* __restrict__ E, const int* __restrict__ tris,
    const int m_tri, float* __restrict__ acc) {
  __shared__ float part[4];
  const int lane = threadIdx.x & 63;
  const int w = threadIdx.x >> 6;
  const int task = blockIdx.x * 4 + w;
  float lse = 0.0f;
  if (task < NB * m_tri) {
    const int b = task / m_tri;
    const int e = task - b * m_tri;
    const int v0 = tris[3 * e];
    const int v1 = tris[3 * e + 1];
    const int v2 = tris[3 * e + 2];
    const uint4* r0 = (const uint4*)(E + (((size_t)(b * NN + v0)) << 10));
    const uint4* r1 = (const uint4*)(E + (((size_t)(b * NN + v1)) << 10));
    const uint4* r2 = (const uint4*)(E + (((size_t)(b * NN + v2)) << 10));
    float s = 0.0f;
#pragma unroll
    for (int j = 0; j < 2; ++j) {
      const int idx = lane + j * 64;
      const uint4 ua = r0[idx];
      const uint4 ub = r1[idx];
      const uint4 uc = r2[idx];
      s = fmaf(blo(ua.x) * blo(ub.x), blo(uc.x), s);
      s = fmaf(bhi(ua.x) * bhi(ub.x), bhi(uc.x), s);
      s = fmaf(blo(ua.y) * blo(ub.y), blo(uc.y), s);
      s = fmaf(bhi(ua.y) * bhi(ub.y), bhi(uc.y), s);
      s = fmaf(blo(ua.z) * blo(ub.z), blo(uc.z), s);
      s = fmaf(bhi(ua.z) * bhi(ub.z), bhi(uc.z), s);
      s = fmaf(blo(ua.w) * blo(ub.w), blo(uc.w), s);
      s = fmaf(bhi(ua.w) * bhi(ub.w), bhi(uc.w), s);
    }
#pragma unroll
    for (int m = 32; m >= 1; m >>= 1) s += __shfl_xor(s, m, 64);
    lse = logf(s);
  }
  if (lane == 0) part[w] = lse;
  __syncthreads();
  if (threadIdx.x == 0) atomicAdd(acc, part[0] + part[1] + part[2] + part[3]);
}

// sum(g*g), exact f32 (dominates output magnitude)
__global__ __launch_bounds__(256) void g2_kernel(const float* __restrict__ g,
                                                 float* __restrict__ acc) {
  __shared__ float part[4];
  const int i = blockIdx.x * 256 + threadIdx.x;   // 65536 float4 = 262144 floats
  const float4 v = ((const float4*)g)[i];
  float s = v.x * v.x + v.y * v.y + v.z * v.z + v.w * v.w;
#pragma unroll
  for (int m = 32; m >= 1; m >>= 1) s += __shfl_xor(s, m, 64);
  const int lane = threadIdx.x & 63;
  const int w = threadIdx.x >> 6;
  if (lane == 0) part[w] = s;
  __syncthreads();
  if (threadIdx.x == 0) atomicAdd(acc + 1, part[0] + part[1] + part[2] + part[3]);
}

__global__ void finalize_kernel(const float* __restrict__ acc,
                                const float* __restrict__ beta, const int ns,
                                float* __restrict__ out) {
  const float ep = -(1.0f / (beta[0] * (float)ns)) * acc[0];
  const float er = -2.0f * acc[1];
  out[0] = (ep + er) / (float)(NB * NN);
}

extern "C" void kernel_launch(void* const* d_in, const int* in_sizes, int n_in,
                              void* d_out, int out_size, void* d_ws, size_t ws_size,
                              hipStream_t stream) {
  const float* g = (const float*)d_in[0];
  const float* patterns = (const float*)d_in[1];
  const float* beta = (const float*)d_in[2];
  const int* edges = (const int*)d_in[3];
  const int* triangles = (const int*)d_in[4];
  const int m_edge = in_sizes[3] / 2;   // 16320
  const int m_tri = in_sizes[4] / 3;    // 16320
  const int ns = m_edge + m_tri;

  float* acc = (float*)d_ws;                       // [0]=lse sum, [1]=g2 sum
  ushort* E = (ushort*)((char*)d_ws + 512);        // (1024,1024) bf16 = 2 MB
  float* out = (float*)d_out;

  hipLaunchKernelGGL(zero_acc_kernel, dim3(1), dim3(64), 0, stream, acc);
  hipLaunchKernelGGL(gemm_exp_kernel, dim3(64, 16), dim3(256), 0, stream,
                     g, patterns, beta, E);
  const int eblocks = (NB * m_edge + 3) / 4;
  hipLaunchKernelGGL(edge_lse_kernel, dim3(eblocks), dim3(256), 0, stream,
                     E, edges, m_edge, acc);
  const int tblocks = (NB * m_tri + 3) / 4;
  hipLaunchKernelGGL(tri_lse_kernel, dim3(tblocks), dim3(256), 0, stream,
                     E, triangles, m_tri, acc);
  hipLaunchKernelGGL(g2_kernel, dim3(256), dim3(256), 0, stream, g, acc);
  hipLaunchKernelGGL(finalize_kernel, dim3(1), dim3(1), 0, stream, acc, beta, ns, out);
}

// Round 2
// 53.695 us; speedup vs baseline: 8.3185x; 8.3185x over previous
//
#include <hip/hip_runtime.h>
#include <hip/hip_bf16.h>

#define NB 4
#define NN 256
#define ND 256
#define NK 1024
#define LOG2E 1.4426950408889634f
#define TRI_BLOCKS 2048

typedef __bf16 bf16x8 __attribute__((ext_vector_type(8)));
typedef float f32x4 __attribute__((ext_vector_type(4)));

__device__ __forceinline__ float blo(unsigned u) { return __uint_as_float(u << 16); }
__device__ __forceinline__ float bhi(unsigned u) { return __uint_as_float(u & 0xffff0000u); }

// h = g @ patterns (bf16 MFMA), fused epilogue: E = bf16(exp(beta*h))
__global__ __launch_bounds__(256) void gemm_exp_kernel(
    const float* __restrict__ A,   // g flattened (B*N, D) = (1024, 256)
    const float* __restrict__ P,   // patterns (D, K) = (256, 1024)
    const float* __restrict__ beta,
    ushort* __restrict__ E) {      // (1024, 1024) bf16 bits
  const int lane = threadIdx.x & 63;
  const int w = threadIdx.x >> 6;
  const int m0 = blockIdx.x * 16;
  const int n0 = blockIdx.y * 64 + w * 16;
  const int r15 = lane & 15;
  const int g4 = lane >> 4;
  const int arow = m0 + r15;
  const int bcol = n0 + r15;

  f32x4 acc = {0.f, 0.f, 0.f, 0.f};
#pragma unroll
  for (int kk = 0; kk < ND; kk += 32) {
    const int kb = kk + g4 * 8;  // same (group,elem)->k map for A and B => layout-safe
    const float* ap = A + arow * ND + kb;
    const float4 a0 = *(const float4*)ap;
    const float4 a1 = *(const float4*)(ap + 4);
    const float* pp = P + kb * NK + bcol;
    bf16x8 af, bfr;
    af[0] = (__bf16)a0.x; af[1] = (__bf16)a0.y; af[2] = (__bf16)a0.z; af[3] = (__bf16)a0.w;
    af[4] = (__bf16)a1.x; af[5] = (__bf16)a1.y; af[6] = (__bf16)a1.z; af[7] = (__bf16)a1.w;
    bfr[0] = (__bf16)pp[0 * NK]; bfr[1] = (__bf16)pp[1 * NK];
    bfr[2] = (__bf16)pp[2 * NK]; bfr[3] = (__bf16)pp[3 * NK];
    bfr[4] = (__bf16)pp[4 * NK]; bfr[5] = (__bf16)pp[5 * NK];
    bfr[6] = (__bf16)pp[6 * NK]; bfr[7] = (__bf16)pp[7 * NK];
    acc = __builtin_amdgcn_mfma_f32_16x16x32_bf16(af, bfr, acc, 0, 0, 0);
  }
  const float c = beta[0] * LOG2E;
#pragma unroll
  for (int r = 0; r < 4; ++r) {
    const int orow = m0 + g4 * 4 + r;   // C/D: col = lane&15, row = (lane>>4)*4 + r (HW-verified)
    const float e = exp2f(c * acc[r]);
    const __bf16 v = (__bf16)e;
    E[orow * NK + bcol] = __builtin_bit_cast(unsigned short, v);
  }
}

// G_b = E_b @ E_b^T via MFMA. Both fragments are contiguous row reads of E.
__global__ __launch_bounds__(256) void gram_kernel(
    const ushort* __restrict__ E, float* __restrict__ G) {
  const int lane = threadIdx.x & 63;
  const int w = threadIdx.x >> 6;
  const int b = blockIdx.z;
  const int m0 = blockIdx.x * 16;
  const int n0 = blockIdx.y * 64 + w * 16;
  const int r15 = lane & 15;
  const int g4 = lane >> 4;
  const ushort* Eb = E + ((size_t)b << 18);        // b * 256 * 1024
  const ushort* ar = Eb + (m0 + r15) * NK;
  const ushort* br = Eb + (n0 + r15) * NK;         // B[k][col] = E[col][k]

  f32x4 acc = {0.f, 0.f, 0.f, 0.f};
#pragma unroll
  for (int kk = 0; kk < NK; kk += 32) {
    const int kb = kk + g4 * 8;
    const bf16x8 af = *(const bf16x8*)(ar + kb);   // 16B aligned
    const bf16x8 bfr = *(const bf16x8*)(br + kb);  // same k-map as A => layout-safe
    acc = __builtin_amdgcn_mfma_f32_16x16x32_bf16(af, bfr, acc, 0, 0, 0);
  }
#pragma unroll
  for (int r = 0; r < 4; ++r) {
    const int orow = m0 + g4 * 4 + r;
    G[(size_t)(((b << 8) | orow) << 8) | (n0 + r15)] = acc[r];
  }
}

// One THREAD per (batch, edge): lse = ln(G_b[v0][v1]); block partial -> part[]
__global__ __launch_bounds__(256) void edge_lse_kernel(
    const float* __restrict__ G, const int* __restrict__ edges,
    const int m_edge, float* __restrict__ part) {
  __shared__ float sp[4];
  const int t = blockIdx.x * 256 + threadIdx.x;
  float v = 0.0f;
  if (t < NB * m_edge) {
    const int b = t / m_edge;
    const int e = t - b * m_edge;
    const int v0 = edges[2 * e];
    const int v1 = edges[2 * e + 1];
    v = logf(G[(size_t)(((b << 8) | v0) << 8) | v1]);
  }
#pragma unroll
  for (int m = 32; m >= 1; m >>= 1) v += __shfl_xor(v, m, 64);
  const int lane = threadIdx.x & 63;
  const int w = threadIdx.x >> 6;
  if (lane == 0) sp[w] = v;
  __syncthreads();
  if (threadIdx.x == 0) part[blockIdx.x] = sp[0] + sp[1] + sp[2] + sp[3];
}

// One wave per (batch, triangle), grid-stride; block partial -> part[] (no atomics)
__global__ __launch_bounds__(256) void tri_lse_kernel(
    const ushort* __restrict__ E, const int* __restrict__ tris,
    const int m_tri, float* __restrict__ part) {
  __shared__ float sp[4];
  const int lane = threadIdx.x & 63;
  const int w = threadIdx.x >> 6;
  const int nwaves = TRI_BLOCKS * 4;
  const int ntask = NB * m_tri;
  float lsum = 0.0f;
  for (int task = blockIdx.x * 4 + w; task < ntask; task += nwaves) {
    const int b = task / m_tri;
    const int e = task - b * m_tri;
    const int v0 = tris[3 * e];
    const int v1 = tris[3 * e + 1];
    const int v2 = tris[3 * e + 2];
    const size_t base = ((size_t)b << 18);
    const uint4* r0 = (const uint4*)(E + base + ((size_t)v0 << 10));
    const uint4* r1 = (const uint4*)(E + base + ((size_t)v1 << 10));
    const uint4* r2 = (const uint4*)(E + base + ((size_t)v2 << 10));
    float s0 = 0.f, s1 = 0.f, s2 = 0.f, s3 = 0.f;
#pragma unroll
    for (int j = 0; j < 2; ++j) {
      const int idx = lane + j * 64;       // 128 uint4 per row, coalesced
      const uint4 ua = r0[idx];
      const uint4 ub = r1[idx];
      const uint4 uc = r2[idx];
      s0 = fmaf(blo(ua.x) * blo(ub.x), blo(uc.x), s0);
      s0 = fmaf(bhi(ua.x) * bhi(ub.x), bhi(uc.x), s0);
      s1 = fmaf(blo(ua.y) * blo(ub.y), blo(uc.y), s1);
      s1 = fmaf(bhi(ua.y) * bhi(ub.y), bhi(uc.y), s1);
      s2 = fmaf(blo(ua.z) * blo(ub.z), blo(uc.z), s2);
      s2 = fmaf(bhi(ua.z) * bhi(ub.z), bhi(uc.z), s2);
      s3 = fmaf(blo(ua.w) * blo(ub.w), blo(uc.w), s3);
      s3 = fmaf(bhi(ua.w) * bhi(ub.w), bhi(uc.w), s3);
    }
    float s = (s0 + s1) + (s2 + s3);
#pragma unroll
    for (int m = 32; m >= 1; m >>= 1) s += __shfl_xor(s, m, 64);
    lsum += logf(s);                       // uniform across lanes after reduce
  }
  if (lane == 0) sp[w] = lsum;
  __syncthreads();
  if (threadIdx.x == 0) part[blockIdx.x] = sp[0] + sp[1] + sp[2] + sp[3];
}

// sum(g*g), block partials (no atomics)
__global__ __launch_bounds__(256) void g2_kernel(const float* __restrict__ g,
                                                 float* __restrict__ part) {
  __shared__ float sp[4];
  const int i = blockIdx.x * 256 + threadIdx.x;   // 65536 float4 = 262144 floats
  const float4 v = ((const float4*)g)[i];
  float s = v.x * v.x + v.y * v.y + v.z * v.z + v.w * v.w;
#pragma unroll
  for (int m = 32; m >= 1; m >>= 1) s += __shfl_xor(s, m, 64);
  const int lane = threadIdx.x & 63;
  const int w = threadIdx.x >> 6;
  if (lane == 0) sp[w] = s;
  __syncthreads();
  if (threadIdx.x == 0) part[blockIdx.x] = sp[0] + sp[1] + sp[2] + sp[3];
}

__global__ __launch_bounds__(256) void reduce_final_kernel(
    const float* __restrict__ pe, const int ne,
    const float* __restrict__ pt, const int nt,
    const float* __restrict__ pg, const int ng,
    const float* __restrict__ beta, const int ns, float* __restrict__ out) {
  __shared__ float sa[4], sb[4];
  float sl = 0.f, sg = 0.f;
  for (int i = threadIdx.x; i < ne; i += 256) sl += pe[i];
  for (int i = threadIdx.x; i < nt; i += 256) sl += pt[i];
  for (int i = threadIdx.x; i < ng; i += 256) sg += pg[i];
#pragma unroll
  for (int m = 32; m >= 1; m >>= 1) {
    sl += __shfl_xor(sl, m, 64);
    sg += __shfl_xor(sg, m, 64);
  }
  const int lane = threadIdx.x & 63;
  const int w = threadIdx.x >> 6;
  if (lane == 0) { sa[w] = sl; sb[w] = sg; }
  __syncthreads();
  if (threadIdx.x == 0) {
    const float L = sa[0] + sa[1] + sa[2] + sa[3];
    const float Gg = sb[0] + sb[1] + sb[2] + sb[3];
    const float ep = -(1.0f / (beta[0] * (float)ns)) * L;
    out[0] = (ep - 2.0f * Gg) / (float)(NB * NN);
  }
}

extern "C" void kernel_launch(void* const* d_in, const int* in_sizes, int n_in,
                              void* d_out, int out_size, void* d_ws, size_t ws_size,
                              hipStream_t stream) {
  const float* g = (const float*)d_in[0];
  const float* patterns = (const float*)d_in[1];
  const float* beta = (const float*)d_in[2];
  const int* edges = (const int*)d_in[3];
  const int* triangles = (const int*)d_in[4];
  const int m_edge = in_sizes[3] / 2;   // 16320
  const int m_tri = in_sizes[4] / 3;    // 16320
  const int ns = m_edge + m_tri;

  // ws layout: E (2MB) | G (1MB) | edge partials (4KB slots) | tri partials | g2 partials
  ushort* E = (ushort*)d_ws;
  float* G = (float*)((char*)d_ws + (2u << 20));
  float* pe = (float*)((char*)d_ws + (3u << 20));
  float* pt = pe + 1024;
  float* pg = pt + TRI_BLOCKS;
  float* out = (float*)d_out;

  hipLaunchKernelGGL(gemm_exp_kernel, dim3(64, 16), dim3(256), 0, stream,
                     g, patterns, beta, E);
  hipLaunchKernelGGL(gram_kernel, dim3(16, 4, NB), dim3(256), 0, stream, E, G);
  const int eblocks = (NB * m_edge + 255) / 256;
  hipLaunchKernelGGL(edge_lse_kernel, dim3(eblocks), dim3(256), 0, stream,
                     G, edges, m_edge, pe);
  hipLaunchKernelGGL(tri_lse_kernel, dim3(TRI_BLOCKS), dim3(256), 0, stream,
                     E, triangles, m_tri, pt);
  hipLaunchKernelGGL(g2_kernel, dim3(256), dim3(256), 0, stream, g, pg);
  hipLaunchKernelGGL(reduce_final_kernel, dim3(1), dim3(256), 0, stream,
                     pe, eblocks, pt, TRI_BLOCKS, pg, 256, beta, ns, out);
}